// Round 10
// baseline (615.989 us; speedup 1.0000x reference)
//
#include <hip/hip_runtime.h>
#include <hip/hip_bf16.h>

#define NCLASSES 6
#define NGRAPHS 16
#define BN_EPS 1e-5f
#define SCAN_BLOCK 256
#define SCAN_ITEMS 16  // 4096 elements per scan block
#define NB2 512        // blocks for bucket count/scatter passes

typedef __attribute__((ext_vector_type(8))) short short8v;
typedef __attribute__((ext_vector_type(4))) float float4v;

__device__ __forceinline__ float bf2f(unsigned short u) {
  union { unsigned int i; float f; } v;
  v.i = ((unsigned int)u) << 16;
  return v.f;
}
__device__ __forceinline__ unsigned short f2bf(float f) {
  union { unsigned int i; float f; } v;
  v.f = f;
  unsigned int b = v.i + 0x7FFFu + ((v.i >> 16) & 1u);
  return (unsigned short)(b >> 16);
}

// ---------------- cast x (fp32) -> bf16 ----------------
__global__ __launch_bounds__(256) void k_cast(const float* __restrict__ x,
                                              unsigned short* __restrict__ hx,
                                              int total4) {
  int i = blockIdx.x * blockDim.x + threadIdx.x;
  int stride = gridDim.x * blockDim.x;
  for (; i < total4; i += stride) {
    float4 f = reinterpret_cast<const float4*>(x)[i];
    ushort4 o;
    o.x = f2bf(f.x); o.y = f2bf(f.y); o.z = f2bf(f.z); o.w = f2bf(f.w);
    reinterpret_cast<ushort4*>(hx)[i] = o;
  }
}

// ---------------- BN-fold into MFMA-fragment-ordered bf16 weights ----------------
// Wfb flat idx = ((((l*2 + mat)*2 + h)*4 + t)*64 + lane)*8 + j
//   holds W_mat[l][k][d]*scale with k = 32h + 8*(lane>>4) + j, d = 16t + (lane&15)
// Sf[(l*2+mat)*64 + d] = be + (b - m)*scale
__global__ void k_fold(const float* __restrict__ W1, const float* __restrict__ b1,
                       const float* __restrict__ g1, const float* __restrict__ be1,
                       const float* __restrict__ m1, const float* __restrict__ v1,
                       const float* __restrict__ W2, const float* __restrict__ b2,
                       const float* __restrict__ g2, const float* __restrict__ be2,
                       const float* __restrict__ m2, const float* __restrict__ v2,
                       unsigned short* __restrict__ Wfb, float* __restrict__ Sf) {
  int idx = blockIdx.x * blockDim.x + threadIdx.x;
  if (idx >= 3 * 2 * 2 * 4 * 64 * 8) return;  // 24576
  int j = idx & 7;
  int lane = (idx >> 3) & 63;
  int t = (idx >> 9) & 3;
  int h = (idx >> 11) & 1;
  int mat = (idx >> 12) & 1;
  int l = idx >> 13;
  int k = 32 * h + 8 * (lane >> 4) + j;
  int d = 16 * t + (lane & 15);
  const float* W = mat ? W2 : W1;
  const float* b = mat ? b2 : b1;
  const float* g = mat ? g2 : g1;
  const float* be = mat ? be2 : be1;
  const float* m = mat ? m2 : m1;
  const float* v = mat ? v2 : v1;
  float scale = g[l * 64 + d] * rsqrtf(v[l * 64 + d] + BN_EPS);
  Wfb[idx] = f2bf(W[(l * 64 + k) * 64 + d] * scale);
  if (h == 0 && j == 0)
    Sf[(l * 2 + mat) * 64 + d] = be[l * 64 + d] + (b[l * 64 + d] - m[l * 64 + d]) * scale;
}

// ---------------- bucketed CSR build ----------------
__global__ __launch_bounds__(256) void k_bcount(const int* __restrict__ dst, int nE,
                                                int chunk, int nbk,
                                                int* __restrict__ hist) {
  __shared__ int lcnt[512];
  for (int i = threadIdx.x; i < nbk; i += 256) lcnt[i] = 0;
  __syncthreads();
  int blk = blockIdx.x;
  int c0 = blk * chunk, c1 = min(nE, c0 + chunk);
  for (int e = c0 + threadIdx.x; e < c1; e += 256) atomicAdd(&lcnt[dst[e] >> 8], 1);
  __syncthreads();
  for (int k = threadIdx.x; k < nbk; k += 256) hist[k * NB2 + blk] = lcnt[k];
}

__global__ __launch_bounds__(SCAN_BLOCK) void k_scan_partial(
    const int* __restrict__ in, int n, int* __restrict__ partials) {
  __shared__ int lds[SCAN_BLOCK];
  int t = threadIdx.x;
  int base = blockIdx.x * SCAN_BLOCK * SCAN_ITEMS + t * SCAN_ITEMS;
  int s = 0;
#pragma unroll
  for (int i = 0; i < SCAN_ITEMS; ++i) {
    int idx = base + i;
    if (idx < n) s += in[idx];
  }
  lds[t] = s;
  __syncthreads();
  for (int off = SCAN_BLOCK / 2; off > 0; off >>= 1) {
    if (t < off) lds[t] += lds[t + off];
    __syncthreads();
  }
  if (t == 0) partials[blockIdx.x] = lds[0];
}

__global__ void k_scan_root(int* __restrict__ partials, int nb) {
  if (threadIdx.x == 0) {
    int run = 0;
    for (int i = 0; i < nb; ++i) {
      int v = partials[i];
      partials[i] = run;
      run += v;
    }
  }
}

__global__ __launch_bounds__(SCAN_BLOCK) void k_scan_write(
    const int* __restrict__ in, int n, const int* __restrict__ partials,
    int* __restrict__ out_excl) {
  __shared__ int lds[SCAN_BLOCK];
  int t = threadIdx.x;
  int base = blockIdx.x * SCAN_BLOCK * SCAN_ITEMS + t * SCAN_ITEMS;
  int local[SCAN_ITEMS];
  int s = 0;
#pragma unroll
  for (int i = 0; i < SCAN_ITEMS; ++i) {
    int idx = base + i;
    int v = (idx < n) ? in[idx] : 0;
    local[i] = v;
    s += v;
  }
  lds[t] = s;
  __syncthreads();
  int val = s;
  for (int off = 1; off < SCAN_BLOCK; off <<= 1) {
    int tmp = (t >= off) ? lds[t - off] : 0;
    __syncthreads();
    val += tmp;
    lds[t] = val;
    __syncthreads();
  }
  int run = partials[blockIdx.x] + val - s;
#pragma unroll
  for (int i = 0; i < SCAN_ITEMS; ++i) {
    int idx = base + i;
    if (idx < n) {
      out_excl[idx] = run;
      run += local[i];
    }
  }
}

__global__ void k_boff(const int* __restrict__ hist_base, int nbk, int nE,
                       int* __restrict__ boff) {
  int t = blockIdx.x * blockDim.x + threadIdx.x;
  if (t < nbk) boff[t] = hist_base[t * NB2];
  if (t == nbk) boff[nbk] = nE;
}

__global__ __launch_bounds__(256) void k_bscatter(const int* __restrict__ src,
                                                  const int* __restrict__ dst, int nE,
                                                  int chunk, int nbk,
                                                  const int* __restrict__ hist_base,
                                                  int* __restrict__ ebuf) {
  __shared__ int cur[512];
  int blk = blockIdx.x;
  for (int k = threadIdx.x; k < nbk; k += 256) cur[k] = hist_base[k * NB2 + blk];
  __syncthreads();
  int c0 = blk * chunk, c1 = min(nE, c0 + chunk);
  for (int e = c0 + threadIdx.x; e < c1; e += 256) {
    int d = dst[e];
    int pos = atomicAdd(&cur[d >> 8], 1);  // LDS atomic
    ebuf[pos] = (src[e] << 8) | (d & 255);
  }
}

__global__ __launch_bounds__(256) void k_bsort(const int* __restrict__ ebuf,
                                               const int* __restrict__ boff, int nbk,
                                               int n, int nE, int* __restrict__ offs,
                                               int* __restrict__ csr_src) {
  __shared__ int cnt[256], sc[256], cur[256];
  int b = blockIdx.x, t = threadIdx.x;
  int e0 = boff[b], e1 = boff[b + 1];
  int node0 = b << 8;
  cnt[t] = 0;
  __syncthreads();
  for (int e = e0 + t; e < e1; e += 256) atomicAdd(&cnt[ebuf[e] & 255], 1);
  __syncthreads();
  int v = cnt[t];
  sc[t] = v;
  __syncthreads();
  int val = v;
  for (int off = 1; off < 256; off <<= 1) {
    int tmp = (t >= off) ? sc[t - off] : 0;
    __syncthreads();
    val += tmp;
    sc[t] = val;
    __syncthreads();
  }
  int excl = val - v;
  int node = node0 + t;
  if (node < n) offs[node] = e0 + excl;
  cur[t] = e0 + excl;
  if (b == nbk - 1 && t == 0) offs[n] = nE;
  __syncthreads();
  for (int e = e0 + t; e < e1; e += 256) {
    int pr = ebuf[e];
    int pos = atomicAdd(&cur[pr & 255], 1);  // LDS atomic
    csr_src[pos] = ((unsigned int)pr) >> 8;
  }
}

// ---------------- gather (bf16 rows): z = h[node] + sum_neigh h ----------------
// 16-deep clamped-index ILP: no serial tail; masked accumulate.
__global__ __launch_bounds__(256, 8) void k_gather(
    const unsigned short* __restrict__ h_in, unsigned short* __restrict__ z,
    const int* __restrict__ offs, const int* __restrict__ csr_src, int n) {
  const int lane = threadIdx.x & 63;
  int wave = blockIdx.x * 4 + (threadIdx.x >> 6);
  int nwaves = gridDim.x * 4;
  for (int node = wave; node < n; node += nwaves) {
    float acc = bf2f(h_in[(size_t)node * 64 + lane]);
    int e0 = __builtin_amdgcn_readfirstlane(offs[node]);
    int e1 = __builtin_amdgcn_readfirstlane(offs[node + 1]);
    float a[8];
#pragma unroll
    for (int i = 0; i < 8; ++i) a[i] = 0.f;
    for (int base = e0; base < e1; base += 16) {
      int idx[16];
      int cnt = e1 - base;  // >0 here
#pragma unroll
      for (int i = 0; i < 16; ++i) {
        int ee = base + i;
        ee = (i < cnt) ? ee : (e1 - 1);
        idx[i] = __builtin_amdgcn_readfirstlane(csr_src[ee]);
      }
#pragma unroll
      for (int i = 0; i < 16; ++i) {
        float v = bf2f(h_in[(size_t)idx[i] * 64 + lane]);
        a[i & 7] += (i < cnt) ? v : 0.f;
      }
    }
    acc += ((a[0] + a[1]) + (a[2] + a[3])) + ((a[4] + a[5]) + (a[6] + a[7]));
    z[(size_t)node * 64 + lane] = f2bf(acc);
  }
}

// ---------------- MFMA MLP: h' = relu(bn2(relu(bn1(z@W1))@W2)) ----------------
// Per wave: 16-node tile. z A-frags: row = lane&15, k = 32h + 8*(lane>>4) + j.
// Weights pre-packed frag-ordered (k_fold). D layout: row=(lane>>4)*4+r, col=lane&15.
// Mid-transpose + coalesced store via wave-private XOR-swizzled LDS tile.
__global__ __launch_bounds__(256, 2) void k_mlp(
    const unsigned short* __restrict__ z_in, unsigned short* __restrict__ h_out,
    const unsigned short* __restrict__ Wfb, const float* __restrict__ Sf, int n) {
  __shared__ __align__(16) unsigned short tile[4][16 * 64];  // 2KB per wave
  const int lane = threadIdx.x & 63;
  const int wslot = threadIdx.x >> 6;
  const int g = lane >> 4, c = lane & 15;
  unsigned short* T = tile[wslot];

  // weight frags [t][h] for each matmul; contiguous ushort8 per lane
  const short8v* Wv = reinterpret_cast<const short8v*>(Wfb);
  short8v w1f[4][2], w2f[4][2];
#pragma unroll
  for (int h = 0; h < 2; ++h)
#pragma unroll
    for (int t = 0; t < 4; ++t) {
      w1f[t][h] = Wv[((0 * 2 + h) * 4 + t) * 64 + lane];
      w2f[t][h] = Wv[((1 * 2 + h) * 4 + t) * 64 + lane];
    }
  float s1v[4], s2v[4];
#pragma unroll
  for (int t = 0; t < 4; ++t) {
    s1v[t] = Sf[c + 16 * t];
    s2v[t] = Sf[64 + c + 16 * t];
  }

  int wave = blockIdx.x * 4 + wslot;
  int nwaves = gridDim.x * 4;
  int ntiles = (n + 15) >> 4;
  for (int tt = wave; tt < ntiles; tt += nwaves) {
    int node0 = tt << 4;
    int arow = node0 + c;
    if (arow >= n) arow = n - 1;
    const short8v* zrow = reinterpret_cast<const short8v*>(z_in + (size_t)arow * 64);
    short8v a0 = zrow[g];      // k = 8g..8g+7
    short8v a1 = zrow[g + 4];  // k = 32+8g..

    float4v c1[4];
#pragma unroll
    for (int t = 0; t < 4; ++t) {
      float4v acc = {s1v[t], s1v[t], s1v[t], s1v[t]};
      acc = __builtin_amdgcn_mfma_f32_16x16x32_bf16(a0, w1f[t][0], acc, 0, 0, 0);
      acc = __builtin_amdgcn_mfma_f32_16x16x32_bf16(a1, w1f[t][1], acc, 0, 0, 0);
      c1[t] = acc;
    }

    // relu -> bf16 -> swizzled LDS (row m = 4g+r, col n1 = c+16t)
#pragma unroll
    for (int t = 0; t < 4; ++t)
#pragma unroll
      for (int r = 0; r < 4; ++r) {
        int m = 4 * g + r;
        int byte = ((c + 16 * t) * 2) ^ ((m & 7) << 4);
        T[(m * 128 + byte) >> 1] = f2bf(fmaxf(c1[t][r], 0.f));
      }
    asm volatile("s_waitcnt lgkmcnt(0)" ::: "memory");
    __builtin_amdgcn_sched_barrier(0);

    // A2-frags: row c, k = 32h + 8g + j
    int rb = c * 128;
    int sw = (c & 7) << 4;
    short8v a20 = *reinterpret_cast<const short8v*>(&T[(rb + ((g * 16) ^ sw)) >> 1]);
    short8v a21 = *reinterpret_cast<const short8v*>(&T[(rb + ((64 + g * 16) ^ sw)) >> 1]);
    asm volatile("s_waitcnt lgkmcnt(0)" ::: "memory");
    __builtin_amdgcn_sched_barrier(0);

    float4v c2[4];
#pragma unroll
    for (int t = 0; t < 4; ++t) {
      float4v acc = {s2v[t], s2v[t], s2v[t], s2v[t]};
      acc = __builtin_amdgcn_mfma_f32_16x16x32_bf16(a20, w2f[t][0], acc, 0, 0, 0);
      acc = __builtin_amdgcn_mfma_f32_16x16x32_bf16(a21, w2f[t][1], acc, 0, 0, 0);
      c2[t] = acc;
    }

    // relu -> bf16 -> swizzled LDS
#pragma unroll
    for (int t = 0; t < 4; ++t)
#pragma unroll
      for (int r = 0; r < 4; ++r) {
        int m = 4 * g + r;
        int byte = ((c + 16 * t) * 2) ^ ((m & 7) << 4);
        T[(m * 128 + byte) >> 1] = f2bf(fmaxf(c2[t][r], 0.f));
      }
    asm volatile("s_waitcnt lgkmcnt(0)" ::: "memory");
    __builtin_amdgcn_sched_barrier(0);

    // coalesced store: lane -> row rho = lane>>2, 32B chunk (lane&3)
    {
      int rho = lane >> 2;
      int node = node0 + rho;
      if (node < n) {
        int cb = (lane & 3) * 32;
        int swr = (rho & 7) << 4;
        short8v v0 = *reinterpret_cast<const short8v*>(&T[(rho * 128 + (cb ^ swr)) >> 1]);
        short8v v1 =
            *reinterpret_cast<const short8v*>(&T[(rho * 128 + ((cb + 16) ^ swr)) >> 1]);
        short8v* orow = reinterpret_cast<short8v*>(h_out + (size_t)node * 64);
        orow[(lane & 3) * 2] = v0;
        orow[(lane & 3) * 2 + 1] = v1;
      }
    }
    asm volatile("s_waitcnt lgkmcnt(0)" ::: "memory");
    __builtin_amdgcn_sched_barrier(0);
  }
}

// ---------------- pooling (bf16 h) ----------------
__global__ __launch_bounds__(256) void k_pool(const unsigned short* __restrict__ h,
                                              const int* __restrict__ batch, int n,
                                              float* __restrict__ gsum,
                                              float* __restrict__ gcnt) {
  __shared__ float lsum[NGRAPHS * 64];
  __shared__ float lcnt[NGRAPHS];
  for (int i = threadIdx.x; i < NGRAPHS * 64; i += 256) lsum[i] = 0.f;
  if (threadIdx.x < NGRAPHS) lcnt[threadIdx.x] = 0.f;
  __syncthreads();
  int lane = threadIdx.x & 63, wslot = threadIdx.x >> 6;
  int wave = blockIdx.x * 4 + wslot, nw = gridDim.x * 4;
  for (int node = wave; node < n; node += nw) {
    int g = batch[node];
    atomicAdd(&lsum[g * 64 + lane], bf2f(h[(size_t)node * 64 + lane]));
    if (lane == 0) atomicAdd(&lcnt[g], 1.f);
  }
  __syncthreads();
  for (int i = threadIdx.x; i < NGRAPHS * 64; i += 256) atomicAdd(&gsum[i], lsum[i]);
  if (threadIdx.x < NGRAPHS) atomicAdd(&gcnt[threadIdx.x], lcnt[threadIdx.x]);
}

// ---------------- heads ----------------
__global__ void k_head(const float* __restrict__ gsum, const float* __restrict__ gcnt,
                       const float* __restrict__ wp, const float* __restrict__ bp,
                       const float* __restrict__ wsec, const float* __restrict__ bsec,
                       float* __restrict__ out) {
  int t = threadIdx.x;
  if (t >= NGRAPHS * NCLASSES) return;
  int g = t / NCLASSES, c = t % NCLASSES;
  float inv = 1.f / fmaxf(gcnt[g], 1.f);
  float p = 0.f, s = 0.f;
  for (int d = 0; d < 64; ++d) {
    float pd = gsum[g * 64 + d] * inv;
    p = fmaf(pd, wp[d * NCLASSES + c], p);
    s = fmaf(pd, wsec[d * NCLASSES + c], s);
  }
  out[t] = p + bp[c];
  out[NGRAPHS * NCLASSES + t] = s + bsec[c];
}

extern "C" void kernel_launch(void* const* d_in, const int* in_sizes, int n_in,
                              void* d_out, int out_size, void* d_ws, size_t ws_size,
                              hipStream_t stream) {
  const float* x = (const float*)d_in[0];
  const int* ei = (const int*)d_in[1];
  const int* batch = (const int*)d_in[2];
  const float* W1 = (const float*)d_in[3];
  const float* b1 = (const float*)d_in[4];
  const float* g1 = (const float*)d_in[5];
  const float* be1 = (const float*)d_in[6];
  const float* m1 = (const float*)d_in[7];
  const float* v1 = (const float*)d_in[8];
  const float* W2 = (const float*)d_in[9];
  const float* b2 = (const float*)d_in[10];
  const float* g2 = (const float*)d_in[11];
  const float* be2 = (const float*)d_in[12];
  const float* m2 = (const float*)d_in[13];
  const float* v2 = (const float*)d_in[14];
  const float* wp = (const float*)d_in[15];
  const float* bp = (const float*)d_in[16];
  const float* wsec = (const float*)d_in[17];
  const float* bsec = (const float*)d_in[18];

  const int nE = in_sizes[1] / 2;
  const int n = in_sizes[0] / 64;
  const int NBK = (n + 255) >> 8;          // buckets of 256 dst nodes
  const int chunk = (nE + NB2 - 1) / NB2;  // edges per count/scatter block

  char* p = (char*)d_ws;
  auto alloc = [&](size_t bytes) {
    char* r = p;
    p += (bytes + 255) & ~(size_t)255;
    return r;
  };
  unsigned short* hx = (unsigned short*)alloc((size_t)n * 64 * 2);
  unsigned short* hA = (unsigned short*)alloc((size_t)n * 64 * 2);
  unsigned short* hB = (unsigned short*)alloc((size_t)n * 64 * 2);
  unsigned short* zbuf = (unsigned short*)alloc((size_t)n * 64 * 2);
  int* csr = (int*)alloc((size_t)nE * 4);
  int* offs = (int*)alloc((size_t)(n + 1) * 4);
  int* hist = (int*)alloc((size_t)NBK * NB2 * 4);
  int* hist_base = (int*)alloc((size_t)NBK * NB2 * 4);
  int* boff = (int*)alloc((size_t)(NBK + 1) * 4);
  int* partials = (int*)alloc(1024 * 4);
  unsigned short* Wfb = (unsigned short*)alloc(3 * 2 * 2 * 4 * 64 * 8 * 2);
  float* Sf = (float*)alloc(3 * 2 * 64 * 4);
  float* gsum = (float*)alloc(NGRAPHS * 64 * 4);
  float* gcnt = (float*)alloc(NGRAPHS * 4);
  int* ebuf = (int*)zbuf;  // overlay: ebuf (6.4MB) dead before layers use zbuf (12.8MB)

  const int* srcA = ei;
  const int* dstA = ei + nE;

  hipMemsetAsync(gsum, 0, NGRAPHS * 64 * 4, stream);
  hipMemsetAsync(gcnt, 0, NGRAPHS * 4, stream);

  k_cast<<<1024, 256, 0, stream>>>(x, hx, n * 64 / 4);
  k_fold<<<96, 256, 0, stream>>>(W1, b1, g1, be1, m1, v1, W2, b2, g2, be2, m2, v2,
                                 Wfb, Sf);

  // ---- bucketed CSR build ----
  k_bcount<<<NB2, 256, 0, stream>>>(dstA, nE, chunk, NBK, hist);
  const int ns = NBK * NB2;
  const int nbs = (ns + SCAN_BLOCK * SCAN_ITEMS - 1) / (SCAN_BLOCK * SCAN_ITEMS);
  k_scan_partial<<<nbs, SCAN_BLOCK, 0, stream>>>(hist, ns, partials);
  k_scan_root<<<1, 64, 0, stream>>>(partials, nbs);
  k_scan_write<<<nbs, SCAN_BLOCK, 0, stream>>>(hist, ns, partials, hist_base);
  k_boff<<<(NBK + 1 + 255) / 256, 256, 0, stream>>>(hist_base, NBK, nE, boff);
  k_bscatter<<<NB2, 256, 0, stream>>>(srcA, dstA, nE, chunk, NBK, hist_base, ebuf);
  k_bsort<<<NBK, 256, 0, stream>>>(ebuf, boff, NBK, n, nE, offs, csr);

  // ---- layers ----
  const int GB = 2048;
  const int MB = 512;
  const unsigned short* hin = hx;
  unsigned short* houts[3] = {hA, hB, hA};
  for (int l = 0; l < 3; ++l) {
    k_gather<<<GB, 256, 0, stream>>>(hin, zbuf, offs, csr, n);
    k_mlp<<<MB, 256, 0, stream>>>(zbuf, houts[l], Wfb + l * 8192, Sf + l * 128, n);
    hin = houts[l];
  }

  k_pool<<<512, 256, 0, stream>>>(hA, batch, n, gsum, gcnt);
  k_head<<<1, 128, 0, stream>>>(gsum, gcnt, wp, bp, wsec, bsec, (float*)d_out);
}

// Round 11
// 373.290 us; speedup vs baseline: 1.6502x; 1.6502x over previous
//
#include <hip/hip_runtime.h>
#include <hip/hip_bf16.h>

#define NCLASSES 6
#define NGRAPHS 16
#define BN_EPS 1e-5f
#define SCAN_BLOCK 256
#define SCAN_ITEMS 16  // 4096 elements per scan block
#define NB2 512        // blocks for bucket count/scatter passes

typedef __attribute__((ext_vector_type(8))) short short8v;
typedef __attribute__((ext_vector_type(4))) float float4v;

__device__ __forceinline__ float bf2f(unsigned short u) {
  union { unsigned int i; float f; } v;
  v.i = ((unsigned int)u) << 16;
  return v.f;
}
__device__ __forceinline__ unsigned short f2bf(float f) {
  union { unsigned int i; float f; } v;
  v.f = f;
  unsigned int b = v.i + 0x7FFFu + ((v.i >> 16) & 1u);
  return (unsigned short)(b >> 16);
}

// ---------------- cast x (fp32) -> bf16 ----------------
__global__ __launch_bounds__(256) void k_cast(const float* __restrict__ x,
                                              unsigned short* __restrict__ hx,
                                              int total4) {
  int i = blockIdx.x * blockDim.x + threadIdx.x;
  int stride = gridDim.x * blockDim.x;
  for (; i < total4; i += stride) {
    float4 f = reinterpret_cast<const float4*>(x)[i];
    ushort4 o;
    o.x = f2bf(f.x); o.y = f2bf(f.y); o.z = f2bf(f.z); o.w = f2bf(f.w);
    reinterpret_cast<ushort4*>(hx)[i] = o;
  }
}

// ---------------- BN-fold into MFMA-fragment-ordered bf16 weights ----------------
// Wfb flat idx = ((((l*2 + mat)*2 + h)*4 + t)*64 + lane)*8 + j
//   holds W_mat[l][k][d]*scale with k = 32h + 8*(lane>>4) + j, d = 16t + (lane&15)
// Sf[(l*2+mat)*64 + d] = be + (b - m)*scale
__global__ void k_fold(const float* __restrict__ W1, const float* __restrict__ b1,
                       const float* __restrict__ g1, const float* __restrict__ be1,
                       const float* __restrict__ m1, const float* __restrict__ v1,
                       const float* __restrict__ W2, const float* __restrict__ b2,
                       const float* __restrict__ g2, const float* __restrict__ be2,
                       const float* __restrict__ m2, const float* __restrict__ v2,
                       unsigned short* __restrict__ Wfb, float* __restrict__ Sf) {
  int idx = blockIdx.x * blockDim.x + threadIdx.x;
  if (idx >= 3 * 2 * 2 * 4 * 64 * 8) return;  // 24576
  int j = idx & 7;
  int lane = (idx >> 3) & 63;
  int t = (idx >> 9) & 3;
  int h = (idx >> 11) & 1;
  int mat = (idx >> 12) & 1;
  int l = idx >> 13;
  int k = 32 * h + 8 * (lane >> 4) + j;
  int d = 16 * t + (lane & 15);
  const float* W = mat ? W2 : W1;
  const float* b = mat ? b2 : b1;
  const float* g = mat ? g2 : g1;
  const float* be = mat ? be2 : be1;
  const float* m = mat ? m2 : m1;
  const float* v = mat ? v2 : v1;
  float scale = g[l * 64 + d] * rsqrtf(v[l * 64 + d] + BN_EPS);
  Wfb[idx] = f2bf(W[(l * 64 + k) * 64 + d] * scale);
  if (h == 0 && j == 0)
    Sf[(l * 2 + mat) * 64 + d] = be[l * 64 + d] + (b[l * 64 + d] - m[l * 64 + d]) * scale;
}

// ---------------- bucketed CSR build ----------------
__global__ __launch_bounds__(256) void k_bcount(const int* __restrict__ dst, int nE,
                                                int chunk, int nbk,
                                                int* __restrict__ hist) {
  __shared__ int lcnt[512];
  for (int i = threadIdx.x; i < nbk; i += 256) lcnt[i] = 0;
  __syncthreads();
  int blk = blockIdx.x;
  int c0 = blk * chunk, c1 = min(nE, c0 + chunk);
  for (int e = c0 + threadIdx.x; e < c1; e += 256) atomicAdd(&lcnt[dst[e] >> 8], 1);
  __syncthreads();
  for (int k = threadIdx.x; k < nbk; k += 256) hist[k * NB2 + blk] = lcnt[k];
}

__global__ __launch_bounds__(SCAN_BLOCK) void k_scan_partial(
    const int* __restrict__ in, int n, int* __restrict__ partials) {
  __shared__ int lds[SCAN_BLOCK];
  int t = threadIdx.x;
  int base = blockIdx.x * SCAN_BLOCK * SCAN_ITEMS + t * SCAN_ITEMS;
  int s = 0;
#pragma unroll
  for (int i = 0; i < SCAN_ITEMS; ++i) {
    int idx = base + i;
    if (idx < n) s += in[idx];
  }
  lds[t] = s;
  __syncthreads();
  for (int off = SCAN_BLOCK / 2; off > 0; off >>= 1) {
    if (t < off) lds[t] += lds[t + off];
    __syncthreads();
  }
  if (t == 0) partials[blockIdx.x] = lds[0];
}

__global__ void k_scan_root(int* __restrict__ partials, int nb) {
  if (threadIdx.x == 0) {
    int run = 0;
    for (int i = 0; i < nb; ++i) {
      int v = partials[i];
      partials[i] = run;
      run += v;
    }
  }
}

__global__ __launch_bounds__(SCAN_BLOCK) void k_scan_write(
    const int* __restrict__ in, int n, const int* __restrict__ partials,
    int* __restrict__ out_excl) {
  __shared__ int lds[SCAN_BLOCK];
  int t = threadIdx.x;
  int base = blockIdx.x * SCAN_BLOCK * SCAN_ITEMS + t * SCAN_ITEMS;
  int local[SCAN_ITEMS];
  int s = 0;
#pragma unroll
  for (int i = 0; i < SCAN_ITEMS; ++i) {
    int idx = base + i;
    int v = (idx < n) ? in[idx] : 0;
    local[i] = v;
    s += v;
  }
  lds[t] = s;
  __syncthreads();
  int val = s;
  for (int off = 1; off < SCAN_BLOCK; off <<= 1) {
    int tmp = (t >= off) ? lds[t - off] : 0;
    __syncthreads();
    val += tmp;
    lds[t] = val;
    __syncthreads();
  }
  int run = partials[blockIdx.x] + val - s;
#pragma unroll
  for (int i = 0; i < SCAN_ITEMS; ++i) {
    int idx = base + i;
    if (idx < n) {
      out_excl[idx] = run;
      run += local[i];
    }
  }
}

__global__ void k_boff(const int* __restrict__ hist_base, int nbk, int nE,
                       int* __restrict__ boff) {
  int t = blockIdx.x * blockDim.x + threadIdx.x;
  if (t < nbk) boff[t] = hist_base[t * NB2];
  if (t == nbk) boff[nbk] = nE;
}

__global__ __launch_bounds__(256) void k_bscatter(const int* __restrict__ src,
                                                  const int* __restrict__ dst, int nE,
                                                  int chunk, int nbk,
                                                  const int* __restrict__ hist_base,
                                                  int* __restrict__ ebuf) {
  __shared__ int cur[512];
  int blk = blockIdx.x;
  for (int k = threadIdx.x; k < nbk; k += 256) cur[k] = hist_base[k * NB2 + blk];
  __syncthreads();
  int c0 = blk * chunk, c1 = min(nE, c0 + chunk);
  for (int e = c0 + threadIdx.x; e < c1; e += 256) {
    int d = dst[e];
    int pos = atomicAdd(&cur[d >> 8], 1);  // LDS atomic
    ebuf[pos] = (src[e] << 8) | (d & 255);
  }
}

__global__ __launch_bounds__(256) void k_bsort(const int* __restrict__ ebuf,
                                               const int* __restrict__ boff, int nbk,
                                               int n, int nE, int* __restrict__ offs,
                                               int* __restrict__ csr_src) {
  __shared__ int cnt[256], sc[256], cur[256];
  int b = blockIdx.x, t = threadIdx.x;
  int e0 = boff[b], e1 = boff[b + 1];
  int node0 = b << 8;
  cnt[t] = 0;
  __syncthreads();
  for (int e = e0 + t; e < e1; e += 256) atomicAdd(&cnt[ebuf[e] & 255], 1);
  __syncthreads();
  int v = cnt[t];
  sc[t] = v;
  __syncthreads();
  int val = v;
  for (int off = 1; off < 256; off <<= 1) {
    int tmp = (t >= off) ? sc[t - off] : 0;
    __syncthreads();
    val += tmp;
    sc[t] = val;
    __syncthreads();
  }
  int excl = val - v;
  int node = node0 + t;
  if (node < n) offs[node] = e0 + excl;
  cur[t] = e0 + excl;
  if (b == nbk - 1 && t == 0) offs[n] = nE;
  __syncthreads();
  for (int e = e0 + t; e < e1; e += 256) {
    int pr = ebuf[e];
    int pos = atomicAdd(&cur[pr & 255], 1);  // LDS atomic
    csr_src[pos] = ((unsigned int)pr) >> 8;
  }
}

// ---------------- gather (bf16 rows): z = h[node] + sum_neigh h ----------------
// (Round-9 proven form: 8-deep unconditional ILP + serial tail; VGPR 20)
__global__ __launch_bounds__(256, 8) void k_gather(
    const unsigned short* __restrict__ h_in, unsigned short* __restrict__ z,
    const int* __restrict__ offs, const int* __restrict__ csr_src, int n) {
  const int lane = threadIdx.x & 63;
  int wave = blockIdx.x * 4 + (threadIdx.x >> 6);
  int nwaves = gridDim.x * 4;
  for (int node = wave; node < n; node += nwaves) {
    float acc = bf2f(h_in[(size_t)node * 64 + lane]);
    int e0 = __builtin_amdgcn_readfirstlane(offs[node]);
    int e1 = __builtin_amdgcn_readfirstlane(offs[node + 1]);
    int e = e0;
    float a0 = 0.f, a1 = 0.f, a2 = 0.f, a3 = 0.f;
    float a4 = 0.f, a5 = 0.f, a6 = 0.f, a7 = 0.f;
    for (; e + 7 < e1; e += 8) {
      int q0 = __builtin_amdgcn_readfirstlane(csr_src[e]);
      int q1 = __builtin_amdgcn_readfirstlane(csr_src[e + 1]);
      int q2 = __builtin_amdgcn_readfirstlane(csr_src[e + 2]);
      int q3 = __builtin_amdgcn_readfirstlane(csr_src[e + 3]);
      int q4 = __builtin_amdgcn_readfirstlane(csr_src[e + 4]);
      int q5 = __builtin_amdgcn_readfirstlane(csr_src[e + 5]);
      int q6 = __builtin_amdgcn_readfirstlane(csr_src[e + 6]);
      int q7 = __builtin_amdgcn_readfirstlane(csr_src[e + 7]);
      a0 += bf2f(h_in[(size_t)q0 * 64 + lane]);
      a1 += bf2f(h_in[(size_t)q1 * 64 + lane]);
      a2 += bf2f(h_in[(size_t)q2 * 64 + lane]);
      a3 += bf2f(h_in[(size_t)q3 * 64 + lane]);
      a4 += bf2f(h_in[(size_t)q4 * 64 + lane]);
      a5 += bf2f(h_in[(size_t)q5 * 64 + lane]);
      a6 += bf2f(h_in[(size_t)q6 * 64 + lane]);
      a7 += bf2f(h_in[(size_t)q7 * 64 + lane]);
    }
    for (; e < e1; ++e) {
      int q = __builtin_amdgcn_readfirstlane(csr_src[e]);
      a0 += bf2f(h_in[(size_t)q * 64 + lane]);
    }
    acc += ((a0 + a1) + (a2 + a3)) + ((a4 + a5) + (a6 + a7));
    z[(size_t)node * 64 + lane] = f2bf(acc);
  }
}

// ---------------- MFMA MLP: h' = relu(bn2(relu(bn1(z@W1))@W2)) ----------------
// Per wave: 16-node tile. z A-frags: row = lane&15, k = 32h + 8*(lane>>4) + j.
// Weights pre-packed frag-ordered (k_fold). D layout: row=(lane>>4)*4+r, col=lane&15.
// Mid-transpose + coalesced store via wave-private XOR-swizzled LDS tile.
__global__ __launch_bounds__(256, 2) void k_mlp(
    const unsigned short* __restrict__ z_in, unsigned short* __restrict__ h_out,
    const unsigned short* __restrict__ Wfb, const float* __restrict__ Sf, int n) {
  __shared__ __align__(16) unsigned short tile[4][16 * 64];  // 2KB per wave
  const int lane = threadIdx.x & 63;
  const int wslot = threadIdx.x >> 6;
  const int g = lane >> 4, c = lane & 15;
  unsigned short* T = tile[wslot];

  // weight frags [t][h] for each matmul; contiguous ushort8 per lane
  const short8v* Wv = reinterpret_cast<const short8v*>(Wfb);
  short8v w1f[4][2], w2f[4][2];
#pragma unroll
  for (int h = 0; h < 2; ++h)
#pragma unroll
    for (int t = 0; t < 4; ++t) {
      w1f[t][h] = Wv[((0 * 2 + h) * 4 + t) * 64 + lane];
      w2f[t][h] = Wv[((1 * 2 + h) * 4 + t) * 64 + lane];
    }
  float s1v[4], s2v[4];
#pragma unroll
  for (int t = 0; t < 4; ++t) {
    s1v[t] = Sf[c + 16 * t];
    s2v[t] = Sf[64 + c + 16 * t];
  }

  int wave = blockIdx.x * 4 + wslot;
  int nwaves = gridDim.x * 4;
  int ntiles = (n + 15) >> 4;
  for (int tt = wave; tt < ntiles; tt += nwaves) {
    int node0 = tt << 4;
    int arow = node0 + c;
    if (arow >= n) arow = n - 1;
    const short8v* zrow = reinterpret_cast<const short8v*>(z_in + (size_t)arow * 64);
    short8v a0 = zrow[g];      // k = 8g..8g+7
    short8v a1 = zrow[g + 4];  // k = 32+8g..

    float4v c1[4];
#pragma unroll
    for (int t = 0; t < 4; ++t) {
      float4v acc = {s1v[t], s1v[t], s1v[t], s1v[t]};
      acc = __builtin_amdgcn_mfma_f32_16x16x32_bf16(a0, w1f[t][0], acc, 0, 0, 0);
      acc = __builtin_amdgcn_mfma_f32_16x16x32_bf16(a1, w1f[t][1], acc, 0, 0, 0);
      c1[t] = acc;
    }

    // relu -> bf16 -> swizzled LDS (row m = 4g+r, col n1 = c+16t)
#pragma unroll
    for (int t = 0; t < 4; ++t)
#pragma unroll
      for (int r = 0; r < 4; ++r) {
        int m = 4 * g + r;
        int byte = ((c + 16 * t) * 2) ^ ((m & 7) << 4);
        T[(m * 128 + byte) >> 1] = f2bf(fmaxf(c1[t][r], 0.f));
      }
    asm volatile("s_waitcnt lgkmcnt(0)" ::: "memory");
    __builtin_amdgcn_sched_barrier(0);

    // A2-frags: row c, k = 32h + 8g + j
    int rb = c * 128;
    int sw = (c & 7) << 4;
    short8v a20 = *reinterpret_cast<const short8v*>(&T[(rb + ((g * 16) ^ sw)) >> 1]);
    short8v a21 = *reinterpret_cast<const short8v*>(&T[(rb + ((64 + g * 16) ^ sw)) >> 1]);
    asm volatile("s_waitcnt lgkmcnt(0)" ::: "memory");
    __builtin_amdgcn_sched_barrier(0);

    float4v c2[4];
#pragma unroll
    for (int t = 0; t < 4; ++t) {
      float4v acc = {s2v[t], s2v[t], s2v[t], s2v[t]};
      acc = __builtin_amdgcn_mfma_f32_16x16x32_bf16(a20, w2f[t][0], acc, 0, 0, 0);
      acc = __builtin_amdgcn_mfma_f32_16x16x32_bf16(a21, w2f[t][1], acc, 0, 0, 0);
      c2[t] = acc;
    }

    // relu -> bf16 -> swizzled LDS
#pragma unroll
    for (int t = 0; t < 4; ++t)
#pragma unroll
      for (int r = 0; r < 4; ++r) {
        int m = 4 * g + r;
        int byte = ((c + 16 * t) * 2) ^ ((m & 7) << 4);
        T[(m * 128 + byte) >> 1] = f2bf(fmaxf(c2[t][r], 0.f));
      }
    asm volatile("s_waitcnt lgkmcnt(0)" ::: "memory");
    __builtin_amdgcn_sched_barrier(0);

    // coalesced store: lane -> row rho = lane>>2, 32B chunk (lane&3)
    {
      int rho = lane >> 2;
      int node = node0 + rho;
      if (node < n) {
        int cb = (lane & 3) * 32;
        int swr = (rho & 7) << 4;
        short8v v0 = *reinterpret_cast<const short8v*>(&T[(rho * 128 + (cb ^ swr)) >> 1]);
        short8v v1 =
            *reinterpret_cast<const short8v*>(&T[(rho * 128 + ((cb + 16) ^ swr)) >> 1]);
        short8v* orow = reinterpret_cast<short8v*>(h_out + (size_t)node * 64);
        orow[(lane & 3) * 2] = v0;
        orow[(lane & 3) * 2 + 1] = v1;
      }
    }
    asm volatile("s_waitcnt lgkmcnt(0)" ::: "memory");
    __builtin_amdgcn_sched_barrier(0);
  }
}

// ---------------- pooling (bf16 h) ----------------
__global__ __launch_bounds__(256) void k_pool(const unsigned short* __restrict__ h,
                                              const int* __restrict__ batch, int n,
                                              float* __restrict__ gsum,
                                              float* __restrict__ gcnt) {
  __shared__ float lsum[NGRAPHS * 64];
  __shared__ float lcnt[NGRAPHS];
  for (int i = threadIdx.x; i < NGRAPHS * 64; i += 256) lsum[i] = 0.f;
  if (threadIdx.x < NGRAPHS) lcnt[threadIdx.x] = 0.f;
  __syncthreads();
  int lane = threadIdx.x & 63, wslot = threadIdx.x >> 6;
  int wave = blockIdx.x * 4 + wslot, nw = gridDim.x * 4;
  for (int node = wave; node < n; node += nw) {
    int g = batch[node];
    atomicAdd(&lsum[g * 64 + lane], bf2f(h[(size_t)node * 64 + lane]));
    if (lane == 0) atomicAdd(&lcnt[g], 1.f);
  }
  __syncthreads();
  for (int i = threadIdx.x; i < NGRAPHS * 64; i += 256) atomicAdd(&gsum[i], lsum[i]);
  if (threadIdx.x < NGRAPHS) atomicAdd(&gcnt[threadIdx.x], lcnt[threadIdx.x]);
}

// ---------------- heads ----------------
__global__ void k_head(const float* __restrict__ gsum, const float* __restrict__ gcnt,
                       const float* __restrict__ wp, const float* __restrict__ bp,
                       const float* __restrict__ wsec, const float* __restrict__ bsec,
                       float* __restrict__ out) {
  int t = threadIdx.x;
  if (t >= NGRAPHS * NCLASSES) return;
  int g = t / NCLASSES, c = t % NCLASSES;
  float inv = 1.f / fmaxf(gcnt[g], 1.f);
  float p = 0.f, s = 0.f;
  for (int d = 0; d < 64; ++d) {
    float pd = gsum[g * 64 + d] * inv;
    p = fmaf(pd, wp[d * NCLASSES + c], p);
    s = fmaf(pd, wsec[d * NCLASSES + c], s);
  }
  out[t] = p + bp[c];
  out[NGRAPHS * NCLASSES + t] = s + bsec[c];
}

extern "C" void kernel_launch(void* const* d_in, const int* in_sizes, int n_in,
                              void* d_out, int out_size, void* d_ws, size_t ws_size,
                              hipStream_t stream) {
  const float* x = (const float*)d_in[0];
  const int* ei = (const int*)d_in[1];
  const int* batch = (const int*)d_in[2];
  const float* W1 = (const float*)d_in[3];
  const float* b1 = (const float*)d_in[4];
  const float* g1 = (const float*)d_in[5];
  const float* be1 = (const float*)d_in[6];
  const float* m1 = (const float*)d_in[7];
  const float* v1 = (const float*)d_in[8];
  const float* W2 = (const float*)d_in[9];
  const float* b2 = (const float*)d_in[10];
  const float* g2 = (const float*)d_in[11];
  const float* be2 = (const float*)d_in[12];
  const float* m2 = (const float*)d_in[13];
  const float* v2 = (const float*)d_in[14];
  const float* wp = (const float*)d_in[15];
  const float* bp = (const float*)d_in[16];
  const float* wsec = (const float*)d_in[17];
  const float* bsec = (const float*)d_in[18];

  const int nE = in_sizes[1] / 2;
  const int n = in_sizes[0] / 64;
  const int NBK = (n + 255) >> 8;          // buckets of 256 dst nodes
  const int chunk = (nE + NB2 - 1) / NB2;  // edges per count/scatter block

  char* p = (char*)d_ws;
  auto alloc = [&](size_t bytes) {
    char* r = p;
    p += (bytes + 255) & ~(size_t)255;
    return r;
  };
  unsigned short* hx = (unsigned short*)alloc((size_t)n * 64 * 2);
  unsigned short* hA = (unsigned short*)alloc((size_t)n * 64 * 2);
  unsigned short* hB = (unsigned short*)alloc((size_t)n * 64 * 2);
  unsigned short* zbuf = (unsigned short*)alloc((size_t)n * 64 * 2);
  int* csr = (int*)alloc((size_t)nE * 4);
  int* offs = (int*)alloc((size_t)(n + 1) * 4);
  int* hist = (int*)alloc((size_t)NBK * NB2 * 4);
  int* hist_base = (int*)alloc((size_t)NBK * NB2 * 4);
  int* boff = (int*)alloc((size_t)(NBK + 1) * 4);
  int* partials = (int*)alloc(1024 * 4);
  unsigned short* Wfb = (unsigned short*)alloc(3 * 2 * 2 * 4 * 64 * 8 * 2);
  float* Sf = (float*)alloc(3 * 2 * 64 * 4);
  float* gsum = (float*)alloc(NGRAPHS * 64 * 4);
  float* gcnt = (float*)alloc(NGRAPHS * 4);
  int* ebuf = (int*)zbuf;  // overlay: ebuf (6.4MB) dead before layers use zbuf (12.8MB)

  const int* srcA = ei;
  const int* dstA = ei + nE;

  hipMemsetAsync(gsum, 0, NGRAPHS * 64 * 4, stream);
  hipMemsetAsync(gcnt, 0, NGRAPHS * 4, stream);

  k_cast<<<1024, 256, 0, stream>>>(x, hx, n * 64 / 4);
  k_fold<<<96, 256, 0, stream>>>(W1, b1, g1, be1, m1, v1, W2, b2, g2, be2, m2, v2,
                                 Wfb, Sf);

  // ---- bucketed CSR build ----
  k_bcount<<<NB2, 256, 0, stream>>>(dstA, nE, chunk, NBK, hist);
  const int ns = NBK * NB2;
  const int nbs = (ns + SCAN_BLOCK * SCAN_ITEMS - 1) / (SCAN_BLOCK * SCAN_ITEMS);
  k_scan_partial<<<nbs, SCAN_BLOCK, 0, stream>>>(hist, ns, partials);
  k_scan_root<<<1, 64, 0, stream>>>(partials, nbs);
  k_scan_write<<<nbs, SCAN_BLOCK, 0, stream>>>(hist, ns, partials, hist_base);
  k_boff<<<(NBK + 1 + 255) / 256, 256, 0, stream>>>(hist_base, NBK, nE, boff);
  k_bscatter<<<NB2, 256, 0, stream>>>(srcA, dstA, nE, chunk, NBK, hist_base, ebuf);
  k_bsort<<<NBK, 256, 0, stream>>>(ebuf, boff, NBK, n, nE, offs, csr);

  // ---- layers ----
  const int GB = 2048;
  const int MB = 512;
  const unsigned short* hin = hx;
  unsigned short* houts[3] = {hA, hB, hA};
  for (int l = 0; l < 3; ++l) {
    k_gather<<<GB, 256, 0, stream>>>(hin, zbuf, offs, csr, n);
    k_mlp<<<MB, 256, 0, stream>>>(zbuf, houts[l], Wfb + l * 8192, Sf + l * 128, n);
    hin = houts[l];
  }

  k_pool<<<512, 256, 0, stream>>>(hA, batch, n, gsum, gcnt);
  k_head<<<1, 128, 0, stream>>>(gsum, gcnt, wp, bp, wsec, bsec, (float*)d_out);
}

// Round 12
// 356.426 us; speedup vs baseline: 1.7282x; 1.0473x over previous
//
#include <hip/hip_runtime.h>
#include <hip/hip_bf16.h>

#define NCLASSES 6
#define NGRAPHS 16
#define BN_EPS 1e-5f
#define SCAN_BLOCK 256
#define SCAN_ITEMS 16  // 4096 elements per scan block
#define NB2 512        // blocks for bucket count/scatter passes

typedef __attribute__((ext_vector_type(8))) short short8v;
typedef __attribute__((ext_vector_type(4))) float float4v;

__device__ __forceinline__ float bf2f(unsigned short u) {
  union { unsigned int i; float f; } v;
  v.i = ((unsigned int)u) << 16;
  return v.f;
}
__device__ __forceinline__ unsigned short f2bf(float f) {
  union { unsigned int i; float f; } v;
  v.f = f;
  unsigned int b = v.i + 0x7FFFu + ((v.i >> 16) & 1u);
  return (unsigned short)(b >> 16);
}

// ---------------- cast x (fp32) -> bf16 ----------------
__global__ __launch_bounds__(256) void k_cast(const float* __restrict__ x,
                                              unsigned short* __restrict__ hx,
                                              int total4) {
  int i = blockIdx.x * blockDim.x + threadIdx.x;
  int stride = gridDim.x * blockDim.x;
  for (; i < total4; i += stride) {
    float4 f = reinterpret_cast<const float4*>(x)[i];
    ushort4 o;
    o.x = f2bf(f.x); o.y = f2bf(f.y); o.z = f2bf(f.z); o.w = f2bf(f.w);
    reinterpret_cast<ushort4*>(hx)[i] = o;
  }
}

// ---------------- BN-fold into MFMA-fragment-ordered bf16 weights ----------------
__global__ void k_fold(const float* __restrict__ W1, const float* __restrict__ b1,
                       const float* __restrict__ g1, const float* __restrict__ be1,
                       const float* __restrict__ m1, const float* __restrict__ v1,
                       const float* __restrict__ W2, const float* __restrict__ b2,
                       const float* __restrict__ g2, const float* __restrict__ be2,
                       const float* __restrict__ m2, const float* __restrict__ v2,
                       unsigned short* __restrict__ Wfb, float* __restrict__ Sf) {
  int idx = blockIdx.x * blockDim.x + threadIdx.x;
  if (idx >= 3 * 2 * 2 * 4 * 64 * 8) return;  // 24576
  int j = idx & 7;
  int lane = (idx >> 3) & 63;
  int t = (idx >> 9) & 3;
  int h = (idx >> 11) & 1;
  int mat = (idx >> 12) & 1;
  int l = idx >> 13;
  int k = 32 * h + 8 * (lane >> 4) + j;
  int d = 16 * t + (lane & 15);
  const float* W = mat ? W2 : W1;
  const float* b = mat ? b2 : b1;
  const float* g = mat ? g2 : g1;
  const float* be = mat ? be2 : be1;
  const float* m = mat ? m2 : m1;
  const float* v = mat ? v2 : v1;
  float scale = g[l * 64 + d] * rsqrtf(v[l * 64 + d] + BN_EPS);
  Wfb[idx] = f2bf(W[(l * 64 + k) * 64 + d] * scale);
  if (h == 0 && j == 0)
    Sf[(l * 2 + mat) * 64 + d] = be[l * 64 + d] + (b[l * 64 + d] - m[l * 64 + d]) * scale;
}

// ---------------- bucketed CSR build ----------------
__global__ __launch_bounds__(256) void k_bcount(const int* __restrict__ dst, int nE,
                                                int chunk, int nbk,
                                                int* __restrict__ hist) {
  __shared__ int lcnt[512];
  for (int i = threadIdx.x; i < nbk; i += 256) lcnt[i] = 0;
  __syncthreads();
  int blk = blockIdx.x;
  int c0 = blk * chunk, c1 = min(nE, c0 + chunk);
  for (int e = c0 + threadIdx.x; e < c1; e += 256) atomicAdd(&lcnt[dst[e] >> 8], 1);
  __syncthreads();
  for (int k = threadIdx.x; k < nbk; k += 256) hist[k * NB2 + blk] = lcnt[k];
}

__global__ __launch_bounds__(SCAN_BLOCK) void k_scan_partial(
    const int* __restrict__ in, int n, int* __restrict__ partials) {
  __shared__ int lds[SCAN_BLOCK];
  int t = threadIdx.x;
  int base = blockIdx.x * SCAN_BLOCK * SCAN_ITEMS + t * SCAN_ITEMS;
  int s = 0;
#pragma unroll
  for (int i = 0; i < SCAN_ITEMS; ++i) {
    int idx = base + i;
    if (idx < n) s += in[idx];
  }
  lds[t] = s;
  __syncthreads();
  for (int off = SCAN_BLOCK / 2; off > 0; off >>= 1) {
    if (t < off) lds[t] += lds[t + off];
    __syncthreads();
  }
  if (t == 0) partials[blockIdx.x] = lds[0];
}

__global__ void k_scan_root(int* __restrict__ partials, int nb) {
  if (threadIdx.x == 0) {
    int run = 0;
    for (int i = 0; i < nb; ++i) {
      int v = partials[i];
      partials[i] = run;
      run += v;
    }
  }
}

__global__ __launch_bounds__(SCAN_BLOCK) void k_scan_write(
    const int* __restrict__ in, int n, const int* __restrict__ partials,
    int* __restrict__ out_excl) {
  __shared__ int lds[SCAN_BLOCK];
  int t = threadIdx.x;
  int base = blockIdx.x * SCAN_BLOCK * SCAN_ITEMS + t * SCAN_ITEMS;
  int local[SCAN_ITEMS];
  int s = 0;
#pragma unroll
  for (int i = 0; i < SCAN_ITEMS; ++i) {
    int idx = base + i;
    int v = (idx < n) ? in[idx] : 0;
    local[i] = v;
    s += v;
  }
  lds[t] = s;
  __syncthreads();
  int val = s;
  for (int off = 1; off < SCAN_BLOCK; off <<= 1) {
    int tmp = (t >= off) ? lds[t - off] : 0;
    __syncthreads();
    val += tmp;
    lds[t] = val;
    __syncthreads();
  }
  int run = partials[blockIdx.x] + val - s;
#pragma unroll
  for (int i = 0; i < SCAN_ITEMS; ++i) {
    int idx = base + i;
    if (idx < n) {
      out_excl[idx] = run;
      run += local[i];
    }
  }
}

__global__ void k_boff(const int* __restrict__ hist_base, int nbk, int nE,
                       int* __restrict__ boff) {
  int t = blockIdx.x * blockDim.x + threadIdx.x;
  if (t < nbk) boff[t] = hist_base[t * NB2];
  if (t == nbk) boff[nbk] = nE;
}

__global__ __launch_bounds__(256) void k_bscatter(const int* __restrict__ src,
                                                  const int* __restrict__ dst, int nE,
                                                  int chunk, int nbk,
                                                  const int* __restrict__ hist_base,
                                                  int* __restrict__ ebuf) {
  __shared__ int cur[512];
  int blk = blockIdx.x;
  for (int k = threadIdx.x; k < nbk; k += 256) cur[k] = hist_base[k * NB2 + blk];
  __syncthreads();
  int c0 = blk * chunk, c1 = min(nE, c0 + chunk);
  for (int e = c0 + threadIdx.x; e < c1; e += 256) {
    int d = dst[e];
    int pos = atomicAdd(&cur[d >> 8], 1);  // LDS atomic
    ebuf[pos] = (src[e] << 8) | (d & 255);
  }
}

// pass A: per-bucket padded totals (each node padded to multiple of 8)
__global__ __launch_bounds__(256) void k_bsortA(const int* __restrict__ ebuf,
                                                const int* __restrict__ boff,
                                                int* __restrict__ pbtot) {
  __shared__ int cnt[256], red[256];
  int b = blockIdx.x, t = threadIdx.x;
  int e0 = boff[b], e1 = boff[b + 1];
  cnt[t] = 0;
  __syncthreads();
  for (int e = e0 + t; e < e1; e += 256) atomicAdd(&cnt[ebuf[e] & 255], 1);
  __syncthreads();
  red[t] = (cnt[t] + 7) & ~7;
  __syncthreads();
  for (int off = 128; off > 0; off >>= 1) {
    if (t < off) red[t] += red[t + off];
    __syncthreads();
  }
  if (t == 0) pbtot[b] = red[0];
}

// exclusive scan of per-bucket padded totals (nbk <= 512); writes offs[n]=total
__global__ __launch_bounds__(512) void k_pscan(const int* __restrict__ pbtot, int nbk,
                                               int* __restrict__ pbase, int n,
                                               int* __restrict__ offs) {
  __shared__ int s[512];
  int t = threadIdx.x;
  int v = (t < nbk) ? pbtot[t] : 0;
  s[t] = v;
  __syncthreads();
  int val = v;
  for (int off = 1; off < 512; off <<= 1) {
    int tmp = (t >= off) ? s[t - off] : 0;
    __syncthreads();
    val += tmp;
    s[t] = val;
    __syncthreads();
  }
  if (t < nbk) pbase[t] = val - v;
  if (t == nbk - 1) offs[n] = val;
}

// pass B: padded offsets + scatter + dummy-fill (dummy index = n -> zero row)
__global__ __launch_bounds__(256) void k_bsortB(const int* __restrict__ ebuf,
                                                const int* __restrict__ boff,
                                                const int* __restrict__ pbase, int n,
                                                int* __restrict__ offs,
                                                int* __restrict__ csr_src) {
  __shared__ int cnt[256], sc[256], cur[256];
  int b = blockIdx.x, t = threadIdx.x;
  int e0 = boff[b], e1 = boff[b + 1];
  int node0 = b << 8;
  cnt[t] = 0;
  __syncthreads();
  for (int e = e0 + t; e < e1; e += 256) atomicAdd(&cnt[ebuf[e] & 255], 1);
  __syncthreads();
  int c = cnt[t];
  int pc = (c + 7) & ~7;
  sc[t] = pc;
  __syncthreads();
  int val = pc;
  for (int off = 1; off < 256; off <<= 1) {
    int tmp = (t >= off) ? sc[t - off] : 0;
    __syncthreads();
    val += tmp;
    sc[t] = val;
    __syncthreads();
  }
  int base = pbase[b] + val - pc;
  int node = node0 + t;
  if (node < n) offs[node] = base;
  cur[t] = base;
  __syncthreads();
  for (int e = e0 + t; e < e1; e += 256) {
    int pr = ebuf[e];
    int pos = atomicAdd(&cur[pr & 255], 1);  // LDS atomic
    csr_src[pos] = ((unsigned int)pr) >> 8;
  }
  __syncthreads();
  for (int i = c; i < pc; ++i) csr_src[base + i] = n;  // dummy -> zero row
}

// ---------------- gather (bf16 rows): z = h[node] + sum_neigh h ----------------
// Padded CSR: (e1-e0) % 8 == 0, no tail. Proven 8-deep unconditional batch.
__global__ __launch_bounds__(256, 8) void k_gather(
    const unsigned short* __restrict__ h_in, unsigned short* __restrict__ z,
    const int* __restrict__ offs, const int* __restrict__ csr_src, int n) {
  const int lane = threadIdx.x & 63;
  int wave = blockIdx.x * 4 + (threadIdx.x >> 6);
  int nwaves = gridDim.x * 4;
  for (int node = wave; node < n; node += nwaves) {
    float acc = bf2f(h_in[(size_t)node * 64 + lane]);
    int e0 = __builtin_amdgcn_readfirstlane(offs[node]);
    int e1 = __builtin_amdgcn_readfirstlane(offs[node + 1]);
    float a0 = 0.f, a1 = 0.f, a2 = 0.f, a3 = 0.f;
    float a4 = 0.f, a5 = 0.f, a6 = 0.f, a7 = 0.f;
    for (int e = e0; e + 7 < e1; e += 8) {
      int q0 = __builtin_amdgcn_readfirstlane(csr_src[e]);
      int q1 = __builtin_amdgcn_readfirstlane(csr_src[e + 1]);
      int q2 = __builtin_amdgcn_readfirstlane(csr_src[e + 2]);
      int q3 = __builtin_amdgcn_readfirstlane(csr_src[e + 3]);
      int q4 = __builtin_amdgcn_readfirstlane(csr_src[e + 4]);
      int q5 = __builtin_amdgcn_readfirstlane(csr_src[e + 5]);
      int q6 = __builtin_amdgcn_readfirstlane(csr_src[e + 6]);
      int q7 = __builtin_amdgcn_readfirstlane(csr_src[e + 7]);
      a0 += bf2f(h_in[(size_t)q0 * 64 + lane]);
      a1 += bf2f(h_in[(size_t)q1 * 64 + lane]);
      a2 += bf2f(h_in[(size_t)q2 * 64 + lane]);
      a3 += bf2f(h_in[(size_t)q3 * 64 + lane]);
      a4 += bf2f(h_in[(size_t)q4 * 64 + lane]);
      a5 += bf2f(h_in[(size_t)q5 * 64 + lane]);
      a6 += bf2f(h_in[(size_t)q6 * 64 + lane]);
      a7 += bf2f(h_in[(size_t)q7 * 64 + lane]);
    }
    acc += ((a0 + a1) + (a2 + a3)) + ((a4 + a5) + (a6 + a7));
    z[(size_t)node * 64 + lane] = f2bf(acc);
  }
}

// ---------------- MFMA MLP (unchanged, verified) ----------------
__global__ __launch_bounds__(256, 2) void k_mlp(
    const unsigned short* __restrict__ z_in, unsigned short* __restrict__ h_out,
    const unsigned short* __restrict__ Wfb, const float* __restrict__ Sf, int n) {
  __shared__ __align__(16) unsigned short tile[4][16 * 64];  // 2KB per wave
  const int lane = threadIdx.x & 63;
  const int wslot = threadIdx.x >> 6;
  const int g = lane >> 4, c = lane & 15;
  unsigned short* T = tile[wslot];

  const short8v* Wv = reinterpret_cast<const short8v*>(Wfb);
  short8v w1f[4][2], w2f[4][2];
#pragma unroll
  for (int h = 0; h < 2; ++h)
#pragma unroll
    for (int t = 0; t < 4; ++t) {
      w1f[t][h] = Wv[((0 * 2 + h) * 4 + t) * 64 + lane];
      w2f[t][h] = Wv[((1 * 2 + h) * 4 + t) * 64 + lane];
    }
  float s1v[4], s2v[4];
#pragma unroll
  for (int t = 0; t < 4; ++t) {
    s1v[t] = Sf[c + 16 * t];
    s2v[t] = Sf[64 + c + 16 * t];
  }

  int wave = blockIdx.x * 4 + wslot;
  int nwaves = gridDim.x * 4;
  int ntiles = (n + 15) >> 4;
  for (int tt = wave; tt < ntiles; tt += nwaves) {
    int node0 = tt << 4;
    int arow = node0 + c;
    if (arow >= n) arow = n - 1;
    const short8v* zrow = reinterpret_cast<const short8v*>(z_in + (size_t)arow * 64);
    short8v a0 = zrow[g];      // k = 8g..8g+7
    short8v a1 = zrow[g + 4];  // k = 32+8g..

    float4v c1[4];
#pragma unroll
    for (int t = 0; t < 4; ++t) {
      float4v acc = {s1v[t], s1v[t], s1v[t], s1v[t]};
      acc = __builtin_amdgcn_mfma_f32_16x16x32_bf16(a0, w1f[t][0], acc, 0, 0, 0);
      acc = __builtin_amdgcn_mfma_f32_16x16x32_bf16(a1, w1f[t][1], acc, 0, 0, 0);
      c1[t] = acc;
    }

#pragma unroll
    for (int t = 0; t < 4; ++t)
#pragma unroll
      for (int r = 0; r < 4; ++r) {
        int m = 4 * g + r;
        int byte = ((c + 16 * t) * 2) ^ ((m & 7) << 4);
        T[(m * 128 + byte) >> 1] = f2bf(fmaxf(c1[t][r], 0.f));
      }
    asm volatile("s_waitcnt lgkmcnt(0)" ::: "memory");
    __builtin_amdgcn_sched_barrier(0);

    int rb = c * 128;
    int sw = (c & 7) << 4;
    short8v a20 = *reinterpret_cast<const short8v*>(&T[(rb + ((g * 16) ^ sw)) >> 1]);
    short8v a21 = *reinterpret_cast<const short8v*>(&T[(rb + ((64 + g * 16) ^ sw)) >> 1]);
    asm volatile("s_waitcnt lgkmcnt(0)" ::: "memory");
    __builtin_amdgcn_sched_barrier(0);

    float4v c2[4];
#pragma unroll
    for (int t = 0; t < 4; ++t) {
      float4v acc = {s2v[t], s2v[t], s2v[t], s2v[t]};
      acc = __builtin_amdgcn_mfma_f32_16x16x32_bf16(a20, w2f[t][0], acc, 0, 0, 0);
      acc = __builtin_amdgcn_mfma_f32_16x16x32_bf16(a21, w2f[t][1], acc, 0, 0, 0);
      c2[t] = acc;
    }

#pragma unroll
    for (int t = 0; t < 4; ++t)
#pragma unroll
      for (int r = 0; r < 4; ++r) {
        int m = 4 * g + r;
        int byte = ((c + 16 * t) * 2) ^ ((m & 7) << 4);
        T[(m * 128 + byte) >> 1] = f2bf(fmaxf(c2[t][r], 0.f));
      }
    asm volatile("s_waitcnt lgkmcnt(0)" ::: "memory");
    __builtin_amdgcn_sched_barrier(0);

    {
      int rho = lane >> 2;
      int node = node0 + rho;
      if (node < n) {
        int cb = (lane & 3) * 32;
        int swr = (rho & 7) << 4;
        short8v v0 = *reinterpret_cast<const short8v*>(&T[(rho * 128 + (cb ^ swr)) >> 1]);
        short8v v1 =
            *reinterpret_cast<const short8v*>(&T[(rho * 128 + ((cb + 16) ^ swr)) >> 1]);
        short8v* orow = reinterpret_cast<short8v*>(h_out + (size_t)node * 64);
        orow[(lane & 3) * 2] = v0;
        orow[(lane & 3) * 2 + 1] = v1;
      }
    }
    asm volatile("s_waitcnt lgkmcnt(0)" ::: "memory");
    __builtin_amdgcn_sched_barrier(0);
  }
}

// ---------------- pooling (bf16 h) ----------------
__global__ __launch_bounds__(256) void k_pool(const unsigned short* __restrict__ h,
                                              const int* __restrict__ batch, int n,
                                              float* __restrict__ gsum,
                                              float* __restrict__ gcnt) {
  __shared__ float lsum[NGRAPHS * 64];
  __shared__ float lcnt[NGRAPHS];
  for (int i = threadIdx.x; i < NGRAPHS * 64; i += 256) lsum[i] = 0.f;
  if (threadIdx.x < NGRAPHS) lcnt[threadIdx.x] = 0.f;
  __syncthreads();
  int lane = threadIdx.x & 63, wslot = threadIdx.x >> 6;
  int wave = blockIdx.x * 4 + wslot, nw = gridDim.x * 4;
  for (int node = wave; node < n; node += nw) {
    int g = batch[node];
    atomicAdd(&lsum[g * 64 + lane], bf2f(h[(size_t)node * 64 + lane]));
    if (lane == 0) atomicAdd(&lcnt[g], 1.f);
  }
  __syncthreads();
  for (int i = threadIdx.x; i < NGRAPHS * 64; i += 256) atomicAdd(&gsum[i], lsum[i]);
  if (threadIdx.x < NGRAPHS) atomicAdd(&gcnt[threadIdx.x], lcnt[threadIdx.x]);
}

// ---------------- heads ----------------
__global__ void k_head(const float* __restrict__ gsum, const float* __restrict__ gcnt,
                       const float* __restrict__ wp, const float* __restrict__ bp,
                       const float* __restrict__ wsec, const float* __restrict__ bsec,
                       float* __restrict__ out) {
  int t = threadIdx.x;
  if (t >= NGRAPHS * NCLASSES) return;
  int g = t / NCLASSES, c = t % NCLASSES;
  float inv = 1.f / fmaxf(gcnt[g], 1.f);
  float p = 0.f, s = 0.f;
  for (int d = 0; d < 64; ++d) {
    float pd = gsum[g * 64 + d] * inv;
    p = fmaf(pd, wp[d * NCLASSES + c], p);
    s = fmaf(pd, wsec[d * NCLASSES + c], s);
  }
  out[t] = p + bp[c];
  out[NGRAPHS * NCLASSES + t] = s + bsec[c];
}

extern "C" void kernel_launch(void* const* d_in, const int* in_sizes, int n_in,
                              void* d_out, int out_size, void* d_ws, size_t ws_size,
                              hipStream_t stream) {
  const float* x = (const float*)d_in[0];
  const int* ei = (const int*)d_in[1];
  const int* batch = (const int*)d_in[2];
  const float* W1 = (const float*)d_in[3];
  const float* b1 = (const float*)d_in[4];
  const float* g1 = (const float*)d_in[5];
  const float* be1 = (const float*)d_in[6];
  const float* m1 = (const float*)d_in[7];
  const float* v1 = (const float*)d_in[8];
  const float* W2 = (const float*)d_in[9];
  const float* b2 = (const float*)d_in[10];
  const float* g2 = (const float*)d_in[11];
  const float* be2 = (const float*)d_in[12];
  const float* m2 = (const float*)d_in[13];
  const float* v2 = (const float*)d_in[14];
  const float* wp = (const float*)d_in[15];
  const float* bp = (const float*)d_in[16];
  const float* wsec = (const float*)d_in[17];
  const float* bsec = (const float*)d_in[18];

  const int nE = in_sizes[1] / 2;
  const int n = in_sizes[0] / 64;
  const int NBK = (n + 255) >> 8;          // buckets of 256 dst nodes
  const int chunk = (nE + NB2 - 1) / NB2;  // edges per count/scatter block

  char* p = (char*)d_ws;
  auto alloc = [&](size_t bytes) {
    char* r = p;
    p += (bytes + 255) & ~(size_t)255;
    return r;
  };
  // h buffers have n+1 rows; row n is the zero "dummy" row for CSR padding
  unsigned short* hx = (unsigned short*)alloc((size_t)(n + 1) * 64 * 2);
  unsigned short* hA = (unsigned short*)alloc((size_t)(n + 1) * 64 * 2);
  unsigned short* hB = (unsigned short*)alloc((size_t)(n + 1) * 64 * 2);
  unsigned short* zbuf = (unsigned short*)alloc((size_t)n * 64 * 2);
  int* csr = (int*)alloc(((size_t)nE + 8 * (size_t)n + 64) * 4);  // padded
  int* offs = (int*)alloc((size_t)(n + 1) * 4);
  int* hist = (int*)alloc((size_t)NBK * NB2 * 4);
  int* hist_base = (int*)alloc((size_t)NBK * NB2 * 4);
  int* boff = (int*)alloc((size_t)(NBK + 1) * 4);
  int* partials = (int*)alloc(1024 * 4);
  int* pbtot = (int*)alloc(512 * 4);
  int* pbase = (int*)alloc(512 * 4);
  unsigned short* Wfb = (unsigned short*)alloc(3 * 2 * 2 * 4 * 64 * 8 * 2);
  float* Sf = (float*)alloc(3 * 2 * 64 * 4);
  float* gsum = (float*)alloc(NGRAPHS * 64 * 4);
  float* gcnt = (float*)alloc(NGRAPHS * 4);
  int* ebuf = (int*)zbuf;  // overlay: ebuf (6.4MB) dead before layers use zbuf (12.8MB)

  const int* srcA = ei;
  const int* dstA = ei + nE;

  hipMemsetAsync(gsum, 0, NGRAPHS * 64 * 4, stream);
  hipMemsetAsync(gcnt, 0, NGRAPHS * 4, stream);
  // zero the dummy rows (ws is re-poisoned before every launch)
  hipMemsetAsync(hx + (size_t)n * 64, 0, 128, stream);
  hipMemsetAsync(hA + (size_t)n * 64, 0, 128, stream);
  hipMemsetAsync(hB + (size_t)n * 64, 0, 128, stream);

  k_cast<<<1024, 256, 0, stream>>>(x, hx, n * 64 / 4);
  k_fold<<<96, 256, 0, stream>>>(W1, b1, g1, be1, m1, v1, W2, b2, g2, be2, m2, v2,
                                 Wfb, Sf);

  // ---- bucketed CSR build (padded to multiples of 8 per node) ----
  k_bcount<<<NB2, 256, 0, stream>>>(dstA, nE, chunk, NBK, hist);
  const int ns = NBK * NB2;
  const int nbs = (ns + SCAN_BLOCK * SCAN_ITEMS - 1) / (SCAN_BLOCK * SCAN_ITEMS);
  k_scan_partial<<<nbs, SCAN_BLOCK, 0, stream>>>(hist, ns, partials);
  k_scan_root<<<1, 64, 0, stream>>>(partials, nbs);
  k_scan_write<<<nbs, SCAN_BLOCK, 0, stream>>>(hist, ns, partials, hist_base);
  k_boff<<<(NBK + 1 + 255) / 256, 256, 0, stream>>>(hist_base, NBK, nE, boff);
  k_bscatter<<<NB2, 256, 0, stream>>>(srcA, dstA, nE, chunk, NBK, hist_base, ebuf);
  k_bsortA<<<NBK, 256, 0, stream>>>(ebuf, boff, pbtot);
  k_pscan<<<1, 512, 0, stream>>>(pbtot, NBK, pbase, n, offs);
  k_bsortB<<<NBK, 256, 0, stream>>>(ebuf, boff, pbase, n, offs, csr);

  // ---- layers ----
  const int GB = 2048;
  const int MB = 512;
  const unsigned short* hin = hx;
  unsigned short* houts[3] = {hA, hB, hA};
  for (int l = 0; l < 3; ++l) {
    k_gather<<<GB, 256, 0, stream>>>(hin, zbuf, offs, csr, n);
    k_mlp<<<MB, 256, 0, stream>>>(zbuf, houts[l], Wfb + l * 8192, Sf + l * 128, n);
    hin = houts[l];
  }

  k_pool<<<512, 256, 0, stream>>>(hA, batch, n, gsum, gcnt);
  k_head<<<1, 128, 0, stream>>>(gsum, gcnt, wp, bp, wsec, bsec, (float*)d_out);
}